// Round 1
// baseline (15099.342 us; speedup 1.0000x reference)
//
#include <hip/hip_runtime.h>
#include <hip/hip_fp16.h>

#define D 64
#define WID 128
#define SSEG 120
#define NSTEP 600
#define NROW 601
#define BATCH 512

// LDS layout: W1/W2 fp32 (swizzled, t-col folded out), W3 fp16 (swizzled),
// plus per-trajectory scratch. Total 153,600 B < 160 KiB.
struct __align__(16) Smem {
  float  w1[WID * WID];   // 64 KB
  float  w2[WID * WID];   // 64 KB
  __half w3[D * WID];     // 16 KB
  float  w1t[WID];        // W1[:,128] (t coefficient)
  float  b1v[WID];
  float  b2v[WID];
  float  b3v[D];
  float  xb[WID];         // MLP input [y_stage | hist]; reused as h2
  float  hb[WID];         // h1
  float  part[4 * D];     // k-split partials
  float  ks[6][D];
  float  ycur[D];
  float  yp0[D];
  float  yp1[D];
};

// One 128-wide layer: acc = dot(w_row[r], xvec) over this thread's k-half.
__device__ __forceinline__ float dot128_half(const float* __restrict__ w,
                                             const float* __restrict__ xvec,
                                             int r, int s) {
  const int sw = r & 7;
  const float4* wr = (const float4*)w + r * 32;
  const float4* xv = (const float4*)xvec;
  float a0 = 0.f, a1 = 0.f, a2 = 0.f, a3 = 0.f;
#pragma unroll
  for (int c = 0; c < 16; c += 4) {
    int ch = (s << 4) + c;
    float4 w0 = wr[(ch + 0) ^ sw]; float4 x0 = xv[ch + 0];
    a0 += w0.x * x0.x + w0.y * x0.y + w0.z * x0.z + w0.w * x0.w;
    float4 w1_ = wr[(ch + 1) ^ sw]; float4 x1 = xv[ch + 1];
    a1 += w1_.x * x1.x + w1_.y * x1.y + w1_.z * x1.z + w1_.w * x1.w;
    float4 w2_ = wr[(ch + 2) ^ sw]; float4 x2 = xv[ch + 2];
    a2 += w2_.x * x2.x + w2_.y * x2.y + w2_.z * x2.z + w2_.w * x2.w;
    float4 w3_ = wr[(ch + 3) ^ sw]; float4 x3 = xv[ch + 3];
    a3 += w3_.x * x3.x + w3_.y * x3.y + w3_.z * x3.z + w3_.w * x3.w;
  }
  return (a0 + a1) + (a2 + a3);
}

__device__ __forceinline__ void mlp_eval(Smem* sm, int tid, float tstage, int kidx) {
  const int r = tid & (WID - 1);
  const int s = tid >> 7;

  // ---- layer 1: hb = relu(W1x*xb + w1t*t + b1) ----
  {
    float a = dot128_half(sm->w1, sm->xb, r, s);
    if (s) sm->part[r] = a;
    __syncthreads();
    if (!s) {
      a += sm->part[r] + sm->b1v[r] + sm->w1t[r] * tstage;
      sm->hb[r] = fmaxf(a, 0.f);
    }
    __syncthreads();
  }
  // ---- layer 2: xb = relu(W2*hb + b2) ----
  {
    float a = dot128_half(sm->w2, sm->hb, r, s);
    if (s) sm->part[r] = a;
    __syncthreads();
    if (!s) {
      a += sm->part[r] + sm->b2v[r];
      sm->xb[r] = fmaxf(a, 0.f);
    }
    __syncthreads();
  }
  // ---- layer 3: ks[kidx] = W3*xb + b3  (W3 fp16, 4-way k-split) ----
  {
    const int r3 = tid & (D - 1);
    const int s3 = tid >> 6;
    const int sw3 = r3 & 7;
    const float4* xv = (const float4*)sm->xb;
    const uint4* wr = (const uint4*)sm->w3 + r3 * 16;
    float a0 = 0.f, a1 = 0.f;
#pragma unroll
    for (int c = 0; c < 4; ++c) {
      int ch = (s3 << 2) + c;
      uint4 wu = wr[ch ^ sw3];
      float4 xa = xv[2 * ch + 0];
      float4 xc = xv[2 * ch + 1];
      float2 f0 = __half22float2(*(const __half2*)&wu.x);
      float2 f1 = __half22float2(*(const __half2*)&wu.y);
      float2 f2 = __half22float2(*(const __half2*)&wu.z);
      float2 f3 = __half22float2(*(const __half2*)&wu.w);
      a0 += f0.x * xa.x + f0.y * xa.y + f1.x * xa.z + f1.y * xa.w;
      a1 += f2.x * xc.x + f2.y * xc.y + f3.x * xc.z + f3.y * xc.w;
    }
    float a = a0 + a1;
    if (s3) sm->part[((s3 - 1) << 6) + r3] = a;
    __syncthreads();
    if (!s3) {
      a += sm->part[r3] + sm->part[D + r3] + sm->part[2 * D + r3];
      sm->ks[kidx][r3] = a + sm->b3v[r3];
    }
    __syncthreads();
  }
}

extern "C" __global__ void __launch_bounds__(256, 1)
NeuralDDEWithTime_46823733461186_kernel(
    const float* __restrict__ gts, const float* __restrict__ gy0,
    const float* __restrict__ gW1, const float* __restrict__ gb1,
    const float* __restrict__ gW2, const float* __restrict__ gb2,
    const float* __restrict__ gW3, const float* __restrict__ gb3,
    float* __restrict__ gout) {
  extern __shared__ float4 smraw4[];
  Smem* sm = (Smem*)smraw4;
  const int tid = threadIdx.x;
  const int b = blockIdx.x;

  const float ts0 = gts[0];
  const float dt = gts[1] - gts[0];

  // ---- stage weights into LDS (swizzle: chunk ^= row&7) ----
  for (int idx = tid; idx < WID * 129; idx += 256) {
    int r = idx / 129, k = idx - r * 129;
    float v = gW1[idx];
    if (k == 128) sm->w1t[r] = v;
    else sm->w1[r * WID + (k ^ ((r & 7) << 2))] = v;
  }
  for (int idx = tid; idx < WID * WID; idx += 256) {
    int r = idx >> 7, k = idx & (WID - 1);
    sm->w2[r * WID + (k ^ ((r & 7) << 2))] = gW2[idx];
  }
  for (int idx = tid; idx < D * WID; idx += 256) {
    int r = idx >> 7, k = idx & (WID - 1);
    sm->w3[r * WID + (k ^ ((r & 7) << 3))] = __float2half(gW3[idx]);
  }
  for (int i = tid; i < WID; i += 256) { sm->b1v[i] = gb1[i]; sm->b2v[i] = gb2[i]; }
  for (int i = tid; i < D; i += 256) sm->b3v[i] = gb3[i];

  const size_t obase = (size_t)b * (NROW * D);
  if (tid < D) {
    float v = gy0[b * D + tid];
    sm->ycur[tid] = v;
    gout[obase + tid] = v;  // dense row 0 = y0
  }
  if (b == 0 && tid == 0) gout[(size_t)BATCH * (NROW * D)] = 600.0f;  // num_steps
  __syncthreads();

  for (int n = 0; n < NSTEP; ++n) {
    float tb = ts0 + (float)n * dt;
    // delayed rows: segment 0 -> constant y0 (row 0); else rows n-120, n-119
    if (tid < D) {
      int r0 = (n >= SSEG) ? (n - SSEG) : 0;
      int r1 = (n >= SSEG) ? (n - SSEG + 1) : 0;
      sm->yp0[tid] = gout[obase + (size_t)r0 * D + tid];
      sm->yp1[tid] = gout[obase + (size_t)r1 * D + tid];
    }
    __syncthreads();

    // ---- k1 ----
    if (tid < D) sm->xb[tid] = sm->ycur[tid];
    else if (tid < 2 * D) sm->xb[tid] = sm->yp0[tid - D];
    __syncthreads();
    mlp_eval(sm, tid, tb, 0);

    // ---- k2 ----
    if (tid < D) sm->xb[tid] = sm->ycur[tid] + dt * (0.2f * sm->ks[0][tid]);
    else if (tid < 2 * D) { int i = tid - D; float p = sm->yp0[i]; sm->xb[tid] = p + 0.2f * (sm->yp1[i] - p); }
    __syncthreads();
    mlp_eval(sm, tid, tb + 0.2f * dt, 1);

    // ---- k3 ----
    if (tid < D) sm->xb[tid] = sm->ycur[tid] + dt * ((3.f / 40.f) * sm->ks[0][tid] + (9.f / 40.f) * sm->ks[1][tid]);
    else if (tid < 2 * D) { int i = tid - D; float p = sm->yp0[i]; sm->xb[tid] = p + 0.3f * (sm->yp1[i] - p); }
    __syncthreads();
    mlp_eval(sm, tid, tb + 0.3f * dt, 2);

    // ---- k4 ----
    if (tid < D) sm->xb[tid] = sm->ycur[tid] + dt * ((44.f / 45.f) * sm->ks[0][tid]
                 - (56.f / 15.f) * sm->ks[1][tid] + (32.f / 9.f) * sm->ks[2][tid]);
    else if (tid < 2 * D) { int i = tid - D; float p = sm->yp0[i]; sm->xb[tid] = p + 0.8f * (sm->yp1[i] - p); }
    __syncthreads();
    mlp_eval(sm, tid, tb + 0.8f * dt, 3);

    // ---- k5 ----
    if (tid < D) sm->xb[tid] = sm->ycur[tid] + dt * ((19372.f / 6561.f) * sm->ks[0][tid]
                 - (25360.f / 2187.f) * sm->ks[1][tid] + (64448.f / 6561.f) * sm->ks[2][tid]
                 - (212.f / 729.f) * sm->ks[3][tid]);
    else if (tid < 2 * D) { int i = tid - D; float p = sm->yp0[i]; sm->xb[tid] = p + (8.f / 9.f) * (sm->yp1[i] - p); }
    __syncthreads();
    mlp_eval(sm, tid, tb + (8.f / 9.f) * dt, 4);

    // ---- k6 (hist = yp1 exactly) ----
    if (tid < D) sm->xb[tid] = sm->ycur[tid] + dt * ((9017.f / 3168.f) * sm->ks[0][tid]
                 - (355.f / 33.f) * sm->ks[1][tid] + (46732.f / 5247.f) * sm->ks[2][tid]
                 + (49.f / 176.f) * sm->ks[3][tid] - (5103.f / 18656.f) * sm->ks[4][tid]);
    else if (tid < 2 * D) sm->xb[tid] = sm->yp1[tid - D];
    __syncthreads();
    mlp_eval(sm, tid, tb + dt, 5);

    // ---- y update + dense-output write ----
    if (tid < D) {
      float yn = sm->ycur[tid] + dt * ((35.f / 384.f) * sm->ks[0][tid]
                 + (500.f / 1113.f) * sm->ks[2][tid] + (125.f / 192.f) * sm->ks[3][tid]
                 - (2187.f / 6784.f) * sm->ks[4][tid] + (11.f / 84.f) * sm->ks[5][tid]);
      sm->ycur[tid] = yn;
      gout[obase + (size_t)(n + 1) * D + tid] = yn;
    }
    __syncthreads();
  }
}

extern "C" void kernel_launch(void* const* d_in, const int* in_sizes, int n_in,
                              void* d_out, int out_size, void* d_ws, size_t ws_size,
                              hipStream_t stream) {
  const float* ts = (const float*)d_in[0];
  const float* y0 = (const float*)d_in[1];
  const float* W1 = (const float*)d_in[2];
  const float* b1 = (const float*)d_in[3];
  const float* W2 = (const float*)d_in[4];
  const float* b2 = (const float*)d_in[5];
  const float* W3 = (const float*)d_in[6];
  const float* b3 = (const float*)d_in[7];
  float* out = (float*)d_out;

  const int smem = (int)sizeof(Smem);  // 153,600 B — needs the >64KB opt-in
  (void)hipFuncSetAttribute((const void*)NeuralDDEWithTime_46823733461186_kernel,
                            hipFuncAttributeMaxDynamicSharedMemorySize, smem);
  hipLaunchKernelGGL(NeuralDDEWithTime_46823733461186_kernel,
                     dim3(BATCH), dim3(256), smem, stream,
                     ts, y0, W1, b1, W2, b2, W3, b3, out);
}

// Round 2
// 4606.915 us; speedup vs baseline: 3.2775x; 3.2775x over previous
//
#include <hip/hip_runtime.h>

typedef _Float16 h2f __attribute__((ext_vector_type(2)));
typedef unsigned short ushort_t;

#define D 64
#define WID 128
#define SSEG 120
#define NSTEP 600
#define NROW 601
#define BATCH 512
#define TPB 512
#define NBLK 256

// All-fp16 weights in LDS, XOR-swizzled uint4 chunks (16 chunks of 8 halfs per row).
// x/h ping-pong buffers as halfs. ks/y-path kept fp32.
struct __align__(16) Smem {
  uint4 w1[WID * 16];   // 32 KB
  uint4 w2[WID * 16];   // 32 KB
  uint4 w3[D * 16];     // 16 KB
  uint4 xA[2 * 16];     // [2 traj][128] halfs — MLP input / L2 output
  uint4 xB[2 * 16];     // [2 traj][128] halfs — L1 output
  float w1t[WID];       // W1[:,128] (t coefficient)
  float b1v[WID];
  float b2v[WID];
  float b3v[D];
  float ks[6][2][D];
};  // 87,808 B -> 1 block/CU

#define CVT16(v) __builtin_bit_cast(ushort_t, (_Float16)(v))

__device__ __forceinline__ float dppadd1(float a) {  // a += lane^1 (quad_perm 1,0,3,2)
  int t = __builtin_amdgcn_update_dpp(0, __builtin_bit_cast(int, a), 0xB1, 0xF, 0xF, true);
  return a + __builtin_bit_cast(float, t);
}
__device__ __forceinline__ float dppadd2(float a) {  // a += lane^2 (quad_perm 2,3,0,1)
  int t = __builtin_amdgcn_update_dpp(0, __builtin_bit_cast(int, a), 0x4E, 0xF, 0xF, true);
  return a + __builtin_bit_cast(float, t);
}
__device__ __forceinline__ float swzadd4(float a) {  // a += lane^4 (ds_swizzle xor4)
  int t = __builtin_amdgcn_ds_swizzle(__builtin_bit_cast(int, a), 0x101F);
  return a + __builtin_bit_cast(float, t);
}

__device__ __forceinline__ float dot8(uint4 w, uint4 x, float acc) {
  acc = __builtin_amdgcn_fdot2(__builtin_bit_cast(h2f, w.x), __builtin_bit_cast(h2f, x.x), acc, false);
  acc = __builtin_amdgcn_fdot2(__builtin_bit_cast(h2f, w.y), __builtin_bit_cast(h2f, x.y), acc, false);
  acc = __builtin_amdgcn_fdot2(__builtin_bit_cast(h2f, w.z), __builtin_bit_cast(h2f, x.z), acc, false);
  acc = __builtin_amdgcn_fdot2(__builtin_bit_cast(h2f, w.w), __builtin_bit_cast(h2f, x.w), acc, false);
  return acc;
}

// 128-out layer: thread (r=tid>>2, q=tid&3) does k-quarter for BOTH trajectories.
// Quad butterfly (DPP) reduces; lane q==0 adds bias(+t), ReLU, writes both halfs.
__device__ __forceinline__ void layer128(const uint4* __restrict__ w,
                                         const uint4* __restrict__ xin,
                                         ushort_t* __restrict__ xout,
                                         const float* __restrict__ bias,
                                         const float* __restrict__ tvec, float tstage,
                                         int tid) {
  const int r = tid >> 2, q = tid & 3, sw = r & 15;
  const uint4* wr = w + r * 16;
  const uint4* x0 = xin;
  const uint4* x1 = xin + 16;
  float a0 = 0.f, a1 = 0.f;
#pragma unroll
  for (int c = 0; c < 4; ++c) {
    const int ch = 4 * q + c;
    uint4 wv = wr[ch ^ sw];
    a0 = dot8(wv, x0[ch], a0);
    a1 = dot8(wv, x1[ch], a1);
  }
  a0 = dppadd2(dppadd1(a0));
  a1 = dppadd2(dppadd1(a1));
  if (q == 0) {
    const float bb = bias[r] + tvec[r] * tstage;
    xout[r]       = CVT16(fmaxf(a0 + bb, 0.f));
    xout[128 + r] = CVT16(fmaxf(a1 + bb, 0.f));
  }
}

// 64-out layer (W3): thread (r=tid>>3, o=tid&7); 8-lane butterfly; lane o==0 writes ks fp32.
__device__ __forceinline__ void layer64(Smem* sm, int kidx, int tid) {
  const int r = tid >> 3, o = tid & 7, sw = r & 15;
  const uint4* wr = sm->w3 + r * 16;
  const uint4* x0 = sm->xA;
  const uint4* x1 = sm->xA + 16;
  float a0 = 0.f, a1 = 0.f;
#pragma unroll
  for (int c = 0; c < 2; ++c) {
    const int ch = 2 * o + c;
    uint4 wv = wr[ch ^ sw];
    a0 = dot8(wv, x0[ch], a0);
    a1 = dot8(wv, x1[ch], a1);
  }
  a0 = swzadd4(dppadd2(dppadd1(a0)));
  a1 = swzadd4(dppadd2(dppadd1(a1)));
  if (o == 0) {
    const float bb = sm->b3v[r];
    sm->ks[kidx][0][r] = a0 + bb;
    sm->ks[kidx][1][r] = a1 + bb;
  }
}

extern "C" __global__ void __launch_bounds__(TPB, 1)
NeuralDDEWithTime_46823733461186_kernel(
    const float* __restrict__ gts, const float* __restrict__ gy0,
    const float* __restrict__ gW1, const float* __restrict__ gb1,
    const float* __restrict__ gW2, const float* __restrict__ gb2,
    const float* __restrict__ gW3, const float* __restrict__ gb3,
    float* __restrict__ gout) {
  extern __shared__ uint4 smraw[];
  Smem* sm = (Smem*)smraw;
  const int tid = threadIdx.x;

  const float ts0 = gts[0];
  const float dt = gts[1] - gts[0];

  // ---- stage fp16 weights, swizzled: chunk slot = (k>>3) ^ (r&15) ----
  ushort_t* w1h = (ushort_t*)sm->w1;
  for (int idx = tid; idx < WID * 129; idx += TPB) {
    int r = idx / 129, k = idx - r * 129;
    float v = gW1[idx];
    if (k == 128) sm->w1t[r] = v;
    else w1h[r * 128 + (((k >> 3) ^ (r & 15)) << 3) + (k & 7)] = CVT16(v);
  }
  ushort_t* w2h = (ushort_t*)sm->w2;
  for (int idx = tid; idx < WID * WID; idx += TPB) {
    int r = idx >> 7, k = idx & 127;
    w2h[r * 128 + (((k >> 3) ^ (r & 15)) << 3) + (k & 7)] = CVT16(gW2[idx]);
  }
  ushort_t* w3h = (ushort_t*)sm->w3;
  for (int idx = tid; idx < D * WID; idx += TPB) {
    int r = idx >> 7, k = idx & 127;
    w3h[r * 128 + (((k >> 3) ^ (r & 15)) << 3) + (k & 7)] = CVT16(gW3[idx]);
  }
  for (int i = tid; i < WID; i += TPB) { sm->b1v[i] = gb1[i]; sm->b2v[i] = gb2[i]; }
  for (int i = tid; i < D; i += TPB) sm->b3v[i] = gb3[i];

  const int traj = (tid >> 6) & 1;
  const int i64 = tid & 63;
  const size_t obt = (size_t)(blockIdx.x * 2 + traj) * (NROW * D);

  // y lives in registers of threads 0..127; history regs in threads 128..255.
  float yreg = 0.f, y0v = 0.f, yp0 = 0.f, yp1 = 0.f;
  if (tid < 128) {
    yreg = gy0[(blockIdx.x * 2 + traj) * D + i64];
    gout[obt + i64] = yreg;  // dense row 0 = y0
  } else if (tid < 256) {
    y0v = gy0[(blockIdx.x * 2 + traj) * D + i64];
    yp0 = y0v;
    yp1 = y0v;
  }
  if (blockIdx.x == 0 && tid == 0) gout[(size_t)BATCH * NROW * D] = 600.0f;  // num_steps

  ushort_t* xh = (ushort_t*)sm->xA;

#define MLP(TSTAGE, KIDX)                                                        \
  __syncthreads();                                                               \
  layer128(sm->w1, sm->xA, (ushort_t*)sm->xB, sm->b1v, sm->w1t, (TSTAGE), tid);  \
  __syncthreads();                                                               \
  layer128(sm->w2, sm->xB, (ushort_t*)sm->xA, sm->b2v, sm->w1t, 0.f, tid);       \
  __syncthreads();                                                               \
  layer64(sm, (KIDX), tid);                                                      \
  __syncthreads();

  for (int n = 0; n < NSTEP; ++n) {
    const float tb = ts0 + (float)n * dt;
    float np0 = 0.f, np1 = 0.f;

    // ---- k1 x-form + next-step history prefetch ----
    if (tid < 128) {
      xh[traj * 128 + i64] = CVT16(yreg);
    } else if (tid < 256) {
      xh[traj * 128 + 64 + i64] = CVT16(yp0);
      const int m = n + 1;
      const int r0 = (m >= SSEG) ? (m - SSEG) : 0;
      const int r1 = (m >= SSEG) ? (m - SSEG + 1) : 0;
      np0 = r0 ? gout[obt + (size_t)r0 * D + i64] : y0v;
      np1 = r1 ? gout[obt + (size_t)r1 * D + i64] : y0v;
    }
    MLP(tb, 0)

    // ---- k2 ----
    if (tid < 128) {
      float xv = yreg + dt * (0.2f * sm->ks[0][traj][i64]);
      xh[traj * 128 + i64] = CVT16(xv);
    } else if (tid < 256) {
      xh[traj * 128 + 64 + i64] = CVT16(yp0 + 0.2f * (yp1 - yp0));
    }
    MLP(tb + 0.2f * dt, 1)

    // ---- k3 ----
    if (tid < 128) {
      float xv = yreg + dt * ((3.f / 40.f) * sm->ks[0][traj][i64] +
                              (9.f / 40.f) * sm->ks[1][traj][i64]);
      xh[traj * 128 + i64] = CVT16(xv);
    } else if (tid < 256) {
      xh[traj * 128 + 64 + i64] = CVT16(yp0 + 0.3f * (yp1 - yp0));
    }
    MLP(tb + 0.3f * dt, 2)

    // ---- k4 ----
    if (tid < 128) {
      float xv = yreg + dt * ((44.f / 45.f) * sm->ks[0][traj][i64] -
                              (56.f / 15.f) * sm->ks[1][traj][i64] +
                              (32.f / 9.f) * sm->ks[2][traj][i64]);
      xh[traj * 128 + i64] = CVT16(xv);
    } else if (tid < 256) {
      xh[traj * 128 + 64 + i64] = CVT16(yp0 + 0.8f * (yp1 - yp0));
    }
    MLP(tb + 0.8f * dt, 3)

    // ---- k5 ----
    if (tid < 128) {
      float xv = yreg + dt * ((19372.f / 6561.f) * sm->ks[0][traj][i64] -
                              (25360.f / 2187.f) * sm->ks[1][traj][i64] +
                              (64448.f / 6561.f) * sm->ks[2][traj][i64] -
                              (212.f / 729.f) * sm->ks[3][traj][i64]);
      xh[traj * 128 + i64] = CVT16(xv);
    } else if (tid < 256) {
      xh[traj * 128 + 64 + i64] = CVT16(yp0 + (8.f / 9.f) * (yp1 - yp0));
    }
    MLP(tb + (8.f / 9.f) * dt, 4)

    // ---- k6 (hist = yp1 exactly) ----
    if (tid < 128) {
      float xv = yreg + dt * ((9017.f / 3168.f) * sm->ks[0][traj][i64] -
                              (355.f / 33.f) * sm->ks[1][traj][i64] +
                              (46732.f / 5247.f) * sm->ks[2][traj][i64] +
                              (49.f / 176.f) * sm->ks[3][traj][i64] -
                              (5103.f / 18656.f) * sm->ks[4][traj][i64]);
      xh[traj * 128 + i64] = CVT16(xv);
    } else if (tid < 256) {
      xh[traj * 128 + 64 + i64] = CVT16(yp1);
    }
    MLP(tb + dt, 5)

    // ---- y update + dense write; rotate prefetched history ----
    if (tid < 128) {
      float yn = yreg + dt * ((35.f / 384.f) * sm->ks[0][traj][i64] +
                              (500.f / 1113.f) * sm->ks[2][traj][i64] +
                              (125.f / 192.f) * sm->ks[3][traj][i64] -
                              (2187.f / 6784.f) * sm->ks[4][traj][i64] +
                              (11.f / 84.f) * sm->ks[5][traj][i64]);
      yreg = yn;
      gout[obt + (size_t)(n + 1) * D + i64] = yn;
    } else if (tid < 256) {
      yp0 = np0;
      yp1 = np1;
    }
    // no barrier needed: next k1 x-form only writes xA, which all threads
    // finished reading before the post-L3 barrier of k6.
  }
#undef MLP
}

extern "C" void kernel_launch(void* const* d_in, const int* in_sizes, int n_in,
                              void* d_out, int out_size, void* d_ws, size_t ws_size,
                              hipStream_t stream) {
  const float* ts = (const float*)d_in[0];
  const float* y0 = (const float*)d_in[1];
  const float* W1 = (const float*)d_in[2];
  const float* b1 = (const float*)d_in[3];
  const float* W2 = (const float*)d_in[4];
  const float* b2 = (const float*)d_in[5];
  const float* W3 = (const float*)d_in[6];
  const float* b3 = (const float*)d_in[7];
  float* out = (float*)d_out;

  const int smem = (int)sizeof(Smem);  // 87,808 B — needs the >64KB opt-in
  (void)hipFuncSetAttribute((const void*)NeuralDDEWithTime_46823733461186_kernel,
                            hipFuncAttributeMaxDynamicSharedMemorySize, smem);
  hipLaunchKernelGGL(NeuralDDEWithTime_46823733461186_kernel,
                     dim3(NBLK), dim3(TPB), smem, stream,
                     ts, y0, W1, b1, W2, b2, W3, b3, out);
}

// Round 3
// 2579.940 us; speedup vs baseline: 5.8526x; 1.7857x over previous
//
#include <hip/hip_runtime.h>

typedef _Float16 h2f __attribute__((ext_vector_type(2)));
typedef unsigned short ushort_t;
typedef unsigned int uint_t;

#define D 64
#define WID 128
#define SSEG 120
#define NSTEP 600
#define NROW 601
#define BATCH 512
#define TPB 256

#define CVT16(v) __builtin_bit_cast(ushort_t, (_Float16)(v))

__device__ __forceinline__ uint_t pack2(float a, float b) {
  h2f v; v.x = (_Float16)a; v.y = (_Float16)b;
  return __builtin_bit_cast(uint_t, v);
}
__device__ __forceinline__ float dppadd1(float a) {  // a += lane^1
  int t = __builtin_amdgcn_update_dpp(0, __builtin_bit_cast(int, a), 0xB1, 0xF, 0xF, true);
  return a + __builtin_bit_cast(float, t);
}
__device__ __forceinline__ float dppadd2(float a) {  // a += lane^2
  int t = __builtin_amdgcn_update_dpp(0, __builtin_bit_cast(int, a), 0x4E, 0xF, 0xF, true);
  return a + __builtin_bit_cast(float, t);
}
__device__ __forceinline__ float dot8(uint4 w, uint4 x, float acc) {
  acc = __builtin_amdgcn_fdot2(__builtin_bit_cast(h2f, w.x), __builtin_bit_cast(h2f, x.x), acc, false);
  acc = __builtin_amdgcn_fdot2(__builtin_bit_cast(h2f, w.y), __builtin_bit_cast(h2f, x.y), acc, false);
  acc = __builtin_amdgcn_fdot2(__builtin_bit_cast(h2f, w.z), __builtin_bit_cast(h2f, x.z), acc, false);
  acc = __builtin_amdgcn_fdot2(__builtin_bit_cast(h2f, w.w), __builtin_bit_cast(h2f, x.w), acc, false);
  return acc;
}

// One block = one trajectory (256 threads, 4 waves). Weights live in VGPRs:
//  L1/L2: lane (r12 = (tid>>1)&127, h12 = tid&1) holds W[r12][64*h12 .. +64) as fp16.
//  L3   : lane (d3 = (tid>>2)&63, q3 = tid&3) holds W3[d3][32*q3 .. +32).
// LDS carries only the 128-half activation vector (ping-pong Xb/Hb, 256 B each).
// Dopri5 state (y, yp0, yp1, k1..k6) lives in the q3==0 lanes' registers.
extern "C" __global__ void __launch_bounds__(TPB, 2)
NeuralDDEWithTime_46823733461186_kernel(
    const float* __restrict__ gts, const float* __restrict__ gy0,
    const float* __restrict__ gW1, const float* __restrict__ gb1,
    const float* __restrict__ gW2, const float* __restrict__ gb2,
    const float* __restrict__ gW3, const float* __restrict__ gb3,
    float* __restrict__ gout) {
  __shared__ uint4 Xb[16];  // 128 halfs: [0..64)=y-part, [64..128)=hist-part
  __shared__ uint4 Hb[16];

  const int tid = threadIdx.x;
  const float ts0 = gts[0];
  const float dt = gts[1] - gts[0];

  const int r12 = (tid >> 1) & 127;
  const int h12 = tid & 1;
  const int q3 = tid & 3;
  const int d3 = (tid >> 2) & 63;

  // ---- weights -> VGPRs (one-time; rows are LLC-resident across blocks) ----
  uint4 w1f[8], w2f[8], w3f[4];
  {
    const float* p = gW1 + r12 * 129 + h12 * 64;
#pragma unroll
    for (int c = 0; c < 8; ++c) {
      uint4 v;
      v.x = pack2(p[8 * c + 0], p[8 * c + 1]);
      v.y = pack2(p[8 * c + 2], p[8 * c + 3]);
      v.z = pack2(p[8 * c + 4], p[8 * c + 5]);
      v.w = pack2(p[8 * c + 6], p[8 * c + 7]);
      w1f[c] = v;
    }
  }
  {
    const float* p = gW2 + r12 * 128 + h12 * 64;
#pragma unroll
    for (int c = 0; c < 8; ++c) {
      uint4 v;
      v.x = pack2(p[8 * c + 0], p[8 * c + 1]);
      v.y = pack2(p[8 * c + 2], p[8 * c + 3]);
      v.z = pack2(p[8 * c + 4], p[8 * c + 5]);
      v.w = pack2(p[8 * c + 6], p[8 * c + 7]);
      w2f[c] = v;
    }
  }
  {
    const float* p = gW3 + d3 * 128 + q3 * 32;
#pragma unroll
    for (int c = 0; c < 4; ++c) {
      uint4 v;
      v.x = pack2(p[8 * c + 0], p[8 * c + 1]);
      v.y = pack2(p[8 * c + 2], p[8 * c + 3]);
      v.z = pack2(p[8 * c + 4], p[8 * c + 5]);
      v.w = pack2(p[8 * c + 6], p[8 * c + 7]);
      w3f[c] = v;
    }
  }
  const float w1t = gW1[r12 * 129 + 128];
  const float b1r = gb1[r12];
  const float b2r = gb2[r12];
  const float b3d = gb3[d3];

  const size_t obt = (size_t)blockIdx.x * (NROW * D);
  float y = 0.f, y0v, yp0 = 0.f, yp1 = 0.f, np0 = 0.f, np1 = 0.f;
  float k1 = 0.f, k2 = 0.f, k3 = 0.f, k4 = 0.f, k5 = 0.f, k6 = 0.f;

  y0v = gy0[blockIdx.x * D + d3];
  if (q3 == 0) {
    y = y0v; yp0 = y0v; yp1 = y0v;
    gout[obt + d3] = y0v;                      // dense row 0 = y0
    ((ushort_t*)Xb)[d3] = CVT16(y0v);          // k1 input: x = [y0 | y0]
    ((ushort_t*)Xb)[D + d3] = CVT16(y0v);
  }
  if (blockIdx.x == 0 && tid == 0) gout[(size_t)BATCH * NROW * D] = 600.0f;  // num_steps
  __syncthreads();

  // MLP3(IN,OUT,TS): L1 IN->OUT, L2 OUT->IN, L3 reads IN; leaves result in KS
  // (valid in all lanes of each quad). Caller's epilogue writes next-x to OUT.
#define MLP3(IN, OUT, TS)                                                       \
  {                                                                             \
    float alo = 0.f, ahi = 0.f;                                                 \
    _Pragma("unroll") for (int c = 0; c < 4; ++c)                               \
        alo = dot8(w1f[c], IN[h12 * 8 + c], alo);                               \
    _Pragma("unroll") for (int c = 0; c < 4; ++c)                               \
        ahi = dot8(w1f[c + 4], IN[h12 * 8 + c + 4], ahi);                       \
    float a = dppadd1(alo + ahi);                                               \
    if (h12 == 0) ((ushort_t*)OUT)[r12] = CVT16(fmaxf(a + b1r + w1t * (TS), 0.f)); \
  }                                                                             \
  __syncthreads();                                                              \
  {                                                                             \
    float alo = 0.f, ahi = 0.f;                                                 \
    _Pragma("unroll") for (int c = 0; c < 4; ++c)                               \
        alo = dot8(w2f[c], OUT[h12 * 8 + c], alo);                              \
    _Pragma("unroll") for (int c = 0; c < 4; ++c)                               \
        ahi = dot8(w2f[c + 4], OUT[h12 * 8 + c + 4], ahi);                      \
    float a = dppadd1(alo + ahi);                                               \
    if (h12 == 0) ((ushort_t*)IN)[r12] = CVT16(fmaxf(a + b2r, 0.f));            \
  }                                                                             \
  __syncthreads();                                                              \
  {                                                                             \
    float alo = 0.f, ahi = 0.f;                                                 \
    alo = dot8(w3f[0], IN[q3 * 4 + 0], alo);                                    \
    alo = dot8(w3f[1], IN[q3 * 4 + 1], alo);                                    \
    ahi = dot8(w3f[2], IN[q3 * 4 + 2], ahi);                                    \
    ahi = dot8(w3f[3], IN[q3 * 4 + 3], ahi);                                    \
    KS = dppadd2(dppadd1(alo + ahi)) + b3d;                                     \
  }

#define XWRITE(OUT, XV, HV)                    \
  ((ushort_t*)OUT)[d3] = CVT16(XV);            \
  ((ushort_t*)OUT)[D + d3] = CVT16(HV);

  for (int n = 0; n < NSTEP; ++n) {
    const float tb = ts0 + (float)n * dt;
    float KS;

    // ---- stage 1: k1 (+ prefetch next step's delayed rows) ----
    MLP3(Xb, Hb, tb)
    k1 = KS;
    if (q3 == 0) {
      const int m = n + 1;
      const int r0 = (m >= SSEG) ? (m - SSEG) : 0;
      const int r1 = (m >= SSEG) ? (m - SSEG + 1) : 0;
      np0 = r0 ? gout[obt + (size_t)r0 * D + d3] : y0v;
      np1 = r1 ? gout[obt + (size_t)r1 * D + d3] : y0v;
      float xv = y + dt * (0.2f * k1);
      float hv = yp0 + 0.2f * (yp1 - yp0);
      XWRITE(Hb, xv, hv)
    }
    __syncthreads();

    // ---- stage 2: k2 ----
    MLP3(Hb, Xb, tb + 0.2f * dt)
    k2 = KS;
    if (q3 == 0) {
      float xv = y + dt * ((3.f / 40.f) * k1 + (9.f / 40.f) * k2);
      float hv = yp0 + 0.3f * (yp1 - yp0);
      XWRITE(Xb, xv, hv)
    }
    __syncthreads();

    // ---- stage 3: k3 ----
    MLP3(Xb, Hb, tb + 0.3f * dt)
    k3 = KS;
    if (q3 == 0) {
      float xv = y + dt * ((44.f / 45.f) * k1 - (56.f / 15.f) * k2 + (32.f / 9.f) * k3);
      float hv = yp0 + 0.8f * (yp1 - yp0);
      XWRITE(Hb, xv, hv)
    }
    __syncthreads();

    // ---- stage 4: k4 ----
    MLP3(Hb, Xb, tb + 0.8f * dt)
    k4 = KS;
    if (q3 == 0) {
      float xv = y + dt * ((19372.f / 6561.f) * k1 - (25360.f / 2187.f) * k2 +
                           (64448.f / 6561.f) * k3 - (212.f / 729.f) * k4);
      float hv = yp0 + (8.f / 9.f) * (yp1 - yp0);
      XWRITE(Xb, xv, hv)
    }
    __syncthreads();

    // ---- stage 5: k5 ----
    MLP3(Xb, Hb, tb + (8.f / 9.f) * dt)
    k5 = KS;
    if (q3 == 0) {
      float xv = y + dt * ((9017.f / 3168.f) * k1 - (355.f / 33.f) * k2 +
                           (46732.f / 5247.f) * k3 + (49.f / 176.f) * k4 -
                           (5103.f / 18656.f) * k5);
      float hv = yp1;  // k6 history is exactly yp1
      XWRITE(Hb, xv, hv)
    }
    __syncthreads();

    // ---- stage 6: k6 + y update + dense write + rotate history ----
    MLP3(Hb, Xb, tb + dt)
    k6 = KS;
    if (q3 == 0) {
      float yn = y + dt * ((35.f / 384.f) * k1 + (500.f / 1113.f) * k3 +
                           (125.f / 192.f) * k4 - (2187.f / 6784.f) * k5 +
                           (11.f / 84.f) * k6);
      y = yn;
      gout[obt + (size_t)(n + 1) * D + d3] = yn;
      yp0 = np0;
      yp1 = np1;
      XWRITE(Xb, yn, yp0)  // next step's k1 input
    }
    __syncthreads();
  }
#undef MLP3
#undef XWRITE
}

extern "C" void kernel_launch(void* const* d_in, const int* in_sizes, int n_in,
                              void* d_out, int out_size, void* d_ws, size_t ws_size,
                              hipStream_t stream) {
  const float* ts = (const float*)d_in[0];
  const float* y0 = (const float*)d_in[1];
  const float* W1 = (const float*)d_in[2];
  const float* b1 = (const float*)d_in[3];
  const float* W2 = (const float*)d_in[4];
  const float* b2 = (const float*)d_in[5];
  const float* W3 = (const float*)d_in[6];
  const float* b3 = (const float*)d_in[7];
  float* out = (float*)d_out;

  hipLaunchKernelGGL(NeuralDDEWithTime_46823733461186_kernel,
                     dim3(BATCH), dim3(TPB), 0, stream,
                     ts, y0, W1, b1, W2, b2, W3, b3, out);
}

// Round 4
// 2538.798 us; speedup vs baseline: 5.9474x; 1.0162x over previous
//
#include <hip/hip_runtime.h>

typedef _Float16 h2f __attribute__((ext_vector_type(2)));
typedef unsigned short ushort_t;
typedef unsigned int uint_t;

#define D 64
#define WID 128
#define SSEG 120
#define NSTEP 600
#define NROW 601
#define BATCH 512
#define TPB 256

#define CVT16(v) __builtin_bit_cast(ushort_t, (_Float16)(v))

static __device__ __forceinline__ uint_t pack2(float a, float b) {
  h2f v; v.x = (_Float16)a; v.y = (_Float16)b;
  return __builtin_bit_cast(uint_t, v);
}
static __device__ __forceinline__ float dppadd1(float a) {  // a += lane^1
  int t = __builtin_amdgcn_update_dpp(0, __builtin_bit_cast(int, a), 0xB1, 0xF, 0xF, true);
  return a + __builtin_bit_cast(float, t);
}
static __device__ __forceinline__ float dppadd2(float a) {  // a += lane^2
  int t = __builtin_amdgcn_update_dpp(0, __builtin_bit_cast(int, a), 0x4E, 0xF, 0xF, true);
  return a + __builtin_bit_cast(float, t);
}
static __device__ __forceinline__ float dot8(uint4 w, uint4 x, float acc) {
  acc = __builtin_amdgcn_fdot2(__builtin_bit_cast(h2f, w.x), __builtin_bit_cast(h2f, x.x), acc, false);
  acc = __builtin_amdgcn_fdot2(__builtin_bit_cast(h2f, w.y), __builtin_bit_cast(h2f, x.y), acc, false);
  acc = __builtin_amdgcn_fdot2(__builtin_bit_cast(h2f, w.z), __builtin_bit_cast(h2f, x.z), acc, false);
  acc = __builtin_amdgcn_fdot2(__builtin_bit_cast(h2f, w.w), __builtin_bit_cast(h2f, x.w), acc, false);
  return acc;
}

// LDS-only barrier: order LDS traffic across waves WITHOUT draining vmcnt
// (__syncthreads drains vmcnt(0), exposing global prefetch/store latency at
// every barrier). sched_barrier(0) fences hoisting per guide rule 18.
static __device__ __forceinline__ void bar_lds() {
  __builtin_amdgcn_sched_barrier(0);
  asm volatile("s_waitcnt lgkmcnt(0)" ::: "memory");
  __builtin_amdgcn_s_barrier();
  __builtin_amdgcn_sched_barrier(0);
}

// One block = one trajectory (256 threads, 4 waves). Weights in VGPRs:
//  L1/L2: lane (r12=(tid>>1)&127, h12=tid&1) holds W[r12][64*h12..+64) fp16.
//  L3   : lane (d3=(tid>>2)&63, q3=tid&3) holds W3[d3][32*q3..+32).
// LDS carries only the 128-half activation vector (ping-pong Xb/Hb).
// Dopri5 state (y, yp0/1, k1..k6) is quad-uniform in ALL lanes (dpp-reduced),
// so epilogues run unmasked and LDS writes are same-addr-same-value.
extern "C" __global__ void __launch_bounds__(TPB, 2)
NeuralDDEWithTime_46823733461186_kernel(
    const float* __restrict__ gts, const float* __restrict__ gy0,
    const float* __restrict__ gW1, const float* __restrict__ gb1,
    const float* __restrict__ gW2, const float* __restrict__ gb2,
    const float* __restrict__ gW3, const float* __restrict__ gb3,
    float* __restrict__ gout) {
  __shared__ uint4 Xb[16];  // 128 halfs: [0..64)=y-part, [64..128)=hist-part
  __shared__ uint4 Hb[16];

  const int tid = threadIdx.x;
  const float ts0 = gts[0];
  const float dt = gts[1] - gts[0];

  const int r12 = (tid >> 1) & 127;
  const int h12 = tid & 1;
  const int q3 = tid & 3;
  const int d3 = (tid >> 2) & 63;

  // ---- weights -> VGPRs (one-time) ----
  uint4 w1f[8], w2f[8], w3f[4];
  {
    const float* p = gW1 + r12 * 129 + h12 * 64;
#pragma unroll
    for (int c = 0; c < 8; ++c) {
      uint4 v;
      v.x = pack2(p[8 * c + 0], p[8 * c + 1]);
      v.y = pack2(p[8 * c + 2], p[8 * c + 3]);
      v.z = pack2(p[8 * c + 4], p[8 * c + 5]);
      v.w = pack2(p[8 * c + 6], p[8 * c + 7]);
      w1f[c] = v;
    }
  }
  {
    const float* p = gW2 + r12 * 128 + h12 * 64;
#pragma unroll
    for (int c = 0; c < 8; ++c) {
      uint4 v;
      v.x = pack2(p[8 * c + 0], p[8 * c + 1]);
      v.y = pack2(p[8 * c + 2], p[8 * c + 3]);
      v.z = pack2(p[8 * c + 4], p[8 * c + 5]);
      v.w = pack2(p[8 * c + 6], p[8 * c + 7]);
      w2f[c] = v;
    }
  }
  {
    const float* p = gW3 + d3 * 128 + q3 * 32;
#pragma unroll
    for (int c = 0; c < 4; ++c) {
      uint4 v;
      v.x = pack2(p[8 * c + 0], p[8 * c + 1]);
      v.y = pack2(p[8 * c + 2], p[8 * c + 3]);
      v.z = pack2(p[8 * c + 4], p[8 * c + 5]);
      v.w = pack2(p[8 * c + 6], p[8 * c + 7]);
      w3f[c] = v;
    }
  }
  const float w1t = gW1[r12 * 129 + 128];
  const float b1r = gb1[r12];
  const float b2r = gb2[r12];
  const float b3d = gb3[d3];

  const size_t obt = (size_t)blockIdx.x * (NROW * D);
  const float* gme = gout + obt + d3;   // this trajectory's dense rows, elem d3

  // state is quad-uniform, lives in ALL lanes
  float y, y0v, yp0, yp1, np0 = 0.f, np1 = 0.f;
  float k1, k2, k3, k4, k5, k6;

  y0v = gy0[blockIdx.x * D + d3];
  y = y0v; yp0 = y0v; yp1 = y0v;
  if (q3 == 0) gout[obt + d3] = y0v;                       // dense row 0 = y0
  ((ushort_t*)Xb)[d3] = CVT16(y0v);                        // k1 input [y0 | y0]
  ((ushort_t*)Xb)[D + d3] = CVT16(y0v);
  if (blockIdx.x == 0 && tid == 0) gout[(size_t)BATCH * NROW * D] = 600.0f;  // num_steps
  bar_lds();

  // ---- MLP3: L1 IN->OUT, L2 OUT->IN, L3 reads IN -> KS (quad-uniform) ----
#define L128(W, BUF, BIAS, TTERM, DST)                                        \
  {                                                                           \
    const uint4* xp = BUF + h12 * 8;                                          \
    uint4 x0 = xp[0], x1 = xp[1], x2 = xp[2], x3 = xp[3];                     \
    uint4 x4 = xp[4], x5 = xp[5], x6 = xp[6], x7 = xp[7];                     \
    __builtin_amdgcn_s_setprio(1);                                            \
    float a0 = dot8(W[0], x0, 0.f), a1 = dot8(W[1], x1, 0.f);                 \
    float a2 = dot8(W[2], x2, 0.f), a3 = dot8(W[3], x3, 0.f);                 \
    a0 = dot8(W[4], x4, a0); a1 = dot8(W[5], x5, a1);                         \
    a2 = dot8(W[6], x6, a2); a3 = dot8(W[7], x7, a3);                         \
    float a = dppadd1((a0 + a1) + (a2 + a3));                                 \
    __builtin_amdgcn_s_setprio(0);                                            \
    ((ushort_t*)DST)[r12] = CVT16(fmaxf(a + (BIAS) + (TTERM), 0.f));          \
  }

#define MLP3(IN, OUT, TS)                                                     \
  L128(w1f, IN, b1r, w1t*(TS), OUT)                                           \
  bar_lds();                                                                  \
  L128(w2f, OUT, b2r, 0.f, IN)                                                \
  bar_lds();                                                                  \
  {                                                                           \
    const uint4* xp = IN + q3 * 4;                                            \
    uint4 x0 = xp[0], x1 = xp[1], x2 = xp[2], x3 = xp[3];                     \
    __builtin_amdgcn_s_setprio(1);                                            \
    float a0 = dot8(w3f[0], x0, 0.f), a1 = dot8(w3f[1], x1, 0.f);             \
    a0 = dot8(w3f[2], x2, a0); a1 = dot8(w3f[3], x3, a1);                     \
    KS = dppadd2(dppadd1(a0 + a1)) + b3d;                                     \
    __builtin_amdgcn_s_setprio(0);                                            \
  }

#define XWRITE(OUT, XV, HV)                    \
  ((ushort_t*)OUT)[d3] = CVT16(XV);            \
  ((ushort_t*)OUT)[D + d3] = CVT16(HV);

  for (int n = 0; n < NSTEP; ++n) {
    const float tb = ts0 + (float)n * dt;
    float KS;

    // ---- history prefetch for step n+1 (max slack; consumed in stage 6) ----
    {
      const int m = n + 1;
      const int r0 = (m >= SSEG) ? (m - SSEG) : 0;
      const int r1 = (m >= SSEG) ? (m - SSEG + 1) : 0;
      np0 = r0 ? gme[(size_t)r0 * D] : y0v;
      np1 = r1 ? gme[(size_t)r1 * D] : y0v;
    }

    // ---- stage 1: k1 ----
    MLP3(Xb, Hb, tb)
    k1 = KS;
    XWRITE(Hb, fmaf(dt, 0.2f * k1, y), fmaf(0.2f, yp1 - yp0, yp0))
    bar_lds();

    // ---- stage 2: k2 ----
    MLP3(Hb, Xb, tb + 0.2f * dt)
    k2 = KS;
    XWRITE(Xb, y + dt * ((3.f / 40.f) * k1 + (9.f / 40.f) * k2),
           fmaf(0.3f, yp1 - yp0, yp0))
    bar_lds();

    // ---- stage 3: k3 ----
    MLP3(Xb, Hb, tb + 0.3f * dt)
    k3 = KS;
    XWRITE(Hb, y + dt * ((44.f / 45.f) * k1 - (56.f / 15.f) * k2 + (32.f / 9.f) * k3),
           fmaf(0.8f, yp1 - yp0, yp0))
    bar_lds();

    // ---- stage 4: k4 ----
    MLP3(Hb, Xb, tb + 0.8f * dt)
    k4 = KS;
    XWRITE(Xb, y + dt * ((19372.f / 6561.f) * k1 - (25360.f / 2187.f) * k2 +
                         (64448.f / 6561.f) * k3 - (212.f / 729.f) * k4),
           fmaf(8.f / 9.f, yp1 - yp0, yp0))
    bar_lds();

    // ---- stage 5: k5 ----
    MLP3(Xb, Hb, tb + (8.f / 9.f) * dt)
    k5 = KS;
    XWRITE(Hb, y + dt * ((9017.f / 3168.f) * k1 - (355.f / 33.f) * k2 +
                         (46732.f / 5247.f) * k3 + (49.f / 176.f) * k4 -
                         (5103.f / 18656.f) * k5),
           yp1)  // k6 history is exactly yp1
    bar_lds();

    // ---- stage 6: k6 + y update + dense write + rotate history ----
    MLP3(Hb, Xb, tb + dt)
    k6 = KS;
    {
      float yn = y + dt * ((35.f / 384.f) * k1 + (500.f / 1113.f) * k3 +
                           (125.f / 192.f) * k4 - (2187.f / 6784.f) * k5 +
                           (11.f / 84.f) * k6);
      y = yn;
      if (q3 == 0) gout[obt + (size_t)(n + 1) * D + d3] = yn;
      yp0 = np0;
      yp1 = np1;
      XWRITE(Xb, yn, yp0)  // next step's k1 input
    }
    bar_lds();
  }
#undef MLP3
#undef L128
#undef XWRITE
}

extern "C" void kernel_launch(void* const* d_in, const int* in_sizes, int n_in,
                              void* d_out, int out_size, void* d_ws, size_t ws_size,
                              hipStream_t stream) {
  const float* ts = (const float*)d_in[0];
  const float* y0 = (const float*)d_in[1];
  const float* W1 = (const float*)d_in[2];
  const float* b1 = (const float*)d_in[3];
  const float* W2 = (const float*)d_in[4];
  const float* b2 = (const float*)d_in[5];
  const float* W3 = (const float*)d_in[6];
  const float* b3 = (const float*)d_in[7];
  float* out = (float*)d_out;

  hipLaunchKernelGGL(NeuralDDEWithTime_46823733461186_kernel,
                     dim3(BATCH), dim3(TPB), 0, stream,
                     ts, y0, W1, b1, W2, b2, W3, b3, out);
}

// Round 5
// 1880.615 us; speedup vs baseline: 8.0289x; 1.3500x over previous
//
#include <hip/hip_runtime.h>

typedef _Float16 half8 __attribute__((ext_vector_type(8)));
typedef float floatx4 __attribute__((ext_vector_type(4)));
typedef unsigned short ushort_t;

#define D 64
#define WID 128
#define SSEG 120
#define NSTEP 600
#define NROW 601
#define BATCH 512
#define TPB 256

#define CVT16(v) __builtin_bit_cast(ushort_t, (_Float16)(v))

static __device__ __forceinline__ floatx4 mfma16(half8 a, half8 b, floatx4 c) {
  return __builtin_amdgcn_mfma_f32_16x16x32_f16(a, b, c, 0, 0, 0);
}

// LDS-only barrier (R4-proven): order LDS traffic without draining vmcnt, so
// global prefetch/stores stay in flight across barriers. sched_barrier fences
// hoisting (guide rule 18).
static __device__ __forceinline__ void bar_lds() {
  __builtin_amdgcn_sched_barrier(0);
  asm volatile("s_waitcnt lgkmcnt(0)" ::: "memory");
  __builtin_amdgcn_s_barrier();
  __builtin_amdgcn_sched_barrier(0);
}

// One block = one trajectory (256 threads, 4 waves), M=1 MFMA formulation.
// Layer = x-frag broadcast reads + mfma_f32_16x16x32_f16 on the (otherwise
// idle) matrix pipe. Wave w owns out-cols [32w,32w+32) for L1/L2 (2 N-tiles)
// and [16w,16w+16) for L3. A-frag rows are all duplicates of the single real
// x row, so every C reg is valid in every lane: state (y, yp, k1..k6) is
// 16-lane-periodic and epilogues run unmasked; LDS/global writes mask lane<16.
extern "C" __global__ void __launch_bounds__(TPB, 2)
NeuralDDEWithTime_46823733461186_kernel(
    const float* __restrict__ gts, const float* __restrict__ gy0,
    const float* __restrict__ gW1, const float* __restrict__ gb1,
    const float* __restrict__ gW2, const float* __restrict__ gb2,
    const float* __restrict__ gW3, const float* __restrict__ gb3,
    float* __restrict__ gout) {
  __shared__ uint4 Xb[16];  // 128 halfs: [0..64)=y-part, [64..128)=hist-part
  __shared__ uint4 Hb[16];

  const int tid = threadIdx.x;
  const int lane = tid & 63;
  const int w = tid >> 6;        // wave 0..3
  const int c = lane & 15;       // out-col within tile / C column
  const int kg = lane >> 4;      // k-group 0..3 (8 halfs each)
  const int kb = kg * 8;
  const bool wr16 = (lane < 16); // writer lanes

  const float ts0 = gts[0];
  const float dt = gts[1] - gts[0];

  // ---- weights -> VGPR B-frags (one-time; scalar loads, init only) ----
  // L1/L2: tiles t=0,1 -> out n = 32w + 16t + c ; L3: n3 = 16w + c
  half8 w1b[2][4], w2b[2][4], w3b[4];
  float b1t[2], w1tt[2], b2t[2];
#pragma unroll
  for (int t = 0; t < 2; ++t) {
    const int n = 32 * w + 16 * t + c;
#pragma unroll
    for (int ks = 0; ks < 4; ++ks) {
      const float* p1 = gW1 + n * 129 + ks * 32 + kb;
      const float* p2 = gW2 + n * 128 + ks * 32 + kb;
      half8 v1, v2;
#pragma unroll
      for (int e = 0; e < 8; ++e) { v1[e] = (_Float16)p1[e]; v2[e] = (_Float16)p2[e]; }
      w1b[t][ks] = v1; w2b[t][ks] = v2;
    }
    b1t[t] = gb1[n];
    w1tt[t] = gW1[n * 129 + 128];
    b2t[t] = gb2[n];
  }
  const int n3 = 16 * w + c;
#pragma unroll
  for (int ks = 0; ks < 4; ++ks) {
    const float* p3 = gW3 + n3 * 128 + ks * 32 + kb;
    half8 v3;
#pragma unroll
    for (int e = 0; e < 8; ++e) v3[e] = (_Float16)p3[e];
    w3b[ks] = v3;
  }
  const float b3r = gb3[n3];

  const int d = 16 * w + c;      // this lane's state element (16-lane periodic)
  const size_t obt = (size_t)blockIdx.x * (NROW * D);
  const float* gme = gout + obt + d;

  float y, y0v, yp0, yp1, np0 = 0.f, np1 = 0.f;
  float k1, k2, k3, k4, k5, k6;

  y0v = gy0[blockIdx.x * D + d];
  y = y0v; yp0 = y0v; yp1 = y0v;
  if (wr16) {
    gout[obt + d] = y0v;                       // dense row 0 = y0
    ((ushort_t*)Xb)[d] = CVT16(y0v);           // k1 input [y0 | y0]
    ((ushort_t*)Xb)[D + d] = CVT16(y0v);
  }
  if (blockIdx.x == 0 && tid == 0) gout[(size_t)BATCH * NROW * D] = 600.0f;  // num_steps
  bar_lds();

  const floatx4 zero4 = {0.f, 0.f, 0.f, 0.f};

  // 128-out layer: IN -> OUT (h = relu(W x + b [+ w1t*t]))
#define L128(WB, BT, TT, IN, OUT)                                             \
  {                                                                           \
    const half8* xp = (const half8*)IN + kg;                                  \
    half8 a0 = xp[0], a1 = xp[4], a2 = xp[8], a3 = xp[12];                    \
    __builtin_amdgcn_s_setprio(1);                                            \
    floatx4 cA = zero4, cB = zero4;                                           \
    cA = mfma16(a0, WB[0][0], cA); cB = mfma16(a0, WB[1][0], cB);             \
    cA = mfma16(a1, WB[0][1], cA); cB = mfma16(a1, WB[1][1], cB);             \
    cA = mfma16(a2, WB[0][2], cA); cB = mfma16(a2, WB[1][2], cB);             \
    cA = mfma16(a3, WB[0][3], cA); cB = mfma16(a3, WB[1][3], cB);             \
    __builtin_amdgcn_s_setprio(0);                                            \
    const float hA = fmaxf(cA[0] + (BT)[0] + (TT)[0], 0.f);                   \
    const float hB = fmaxf(cB[0] + (BT)[1] + (TT)[1], 0.f);                   \
    if (wr16) {                                                               \
      ((ushort_t*)OUT)[32 * w + c] = CVT16(hA);                               \
      ((ushort_t*)OUT)[32 * w + 16 + c] = CVT16(hB);                          \
    }                                                                         \
  }

  // MLP3: L1 IN->OUT, L2 OUT->IN, L3 reads IN -> KS (valid in all lanes).
#define MLP3(IN, OUT, TS)                                                     \
  {                                                                           \
    const float tterm1[2] = {w1tt[0] * (TS), w1tt[1] * (TS)};                 \
    L128(w1b, b1t, tterm1, IN, OUT)                                           \
    bar_lds();                                                                \
    const float tz[2] = {0.f, 0.f};                                           \
    L128(w2b, b2t, tz, OUT, IN)                                               \
    bar_lds();                                                                \
    const half8* xp = (const half8*)IN + kg;                                  \
    half8 a0 = xp[0], a1 = xp[4], a2 = xp[8], a3 = xp[12];                    \
    __builtin_amdgcn_s_setprio(1);                                            \
    floatx4 c3 = zero4;                                                       \
    c3 = mfma16(a0, w3b[0], c3); c3 = mfma16(a1, w3b[1], c3);                 \
    c3 = mfma16(a2, w3b[2], c3); c3 = mfma16(a3, w3b[3], c3);                 \
    __builtin_amdgcn_s_setprio(0);                                            \
    KS = c3[0] + b3r;                                                         \
  }

#define XWRITE(OUT, XV, HV)                    \
  if (wr16) {                                  \
    ((ushort_t*)OUT)[d] = CVT16(XV);           \
    ((ushort_t*)OUT)[D + d] = CVT16(HV);       \
  }

  for (int n = 0; n < NSTEP; ++n) {
    const float tb = ts0 + (float)n * dt;
    float KS;

    // ---- history prefetch for step n+1 (consumed in stage-6 epilogue) ----
    {
      const int m = n + 1;
      const int r0 = (m >= SSEG) ? (m - SSEG) : 0;
      const int r1 = (m >= SSEG) ? (m - SSEG + 1) : 0;
      np0 = r0 ? gme[(size_t)r0 * D] : y0v;
      np1 = r1 ? gme[(size_t)r1 * D] : y0v;
    }

    // ---- stage 1: k1 ----
    MLP3(Xb, Hb, tb)
    k1 = KS;
    XWRITE(Hb, fmaf(dt, 0.2f * k1, y), fmaf(0.2f, yp1 - yp0, yp0))
    bar_lds();

    // ---- stage 2: k2 ----
    MLP3(Hb, Xb, tb + 0.2f * dt)
    k2 = KS;
    XWRITE(Xb, y + dt * ((3.f / 40.f) * k1 + (9.f / 40.f) * k2),
           fmaf(0.3f, yp1 - yp0, yp0))
    bar_lds();

    // ---- stage 3: k3 ----
    MLP3(Xb, Hb, tb + 0.3f * dt)
    k3 = KS;
    XWRITE(Hb, y + dt * ((44.f / 45.f) * k1 - (56.f / 15.f) * k2 + (32.f / 9.f) * k3),
           fmaf(0.8f, yp1 - yp0, yp0))
    bar_lds();

    // ---- stage 4: k4 ----
    MLP3(Hb, Xb, tb + 0.8f * dt)
    k4 = KS;
    XWRITE(Xb, y + dt * ((19372.f / 6561.f) * k1 - (25360.f / 2187.f) * k2 +
                         (64448.f / 6561.f) * k3 - (212.f / 729.f) * k4),
           fmaf(8.f / 9.f, yp1 - yp0, yp0))
    bar_lds();

    // ---- stage 5: k5 ----
    MLP3(Xb, Hb, tb + (8.f / 9.f) * dt)
    k5 = KS;
    XWRITE(Hb, y + dt * ((9017.f / 3168.f) * k1 - (355.f / 33.f) * k2 +
                         (46732.f / 5247.f) * k3 + (49.f / 176.f) * k4 -
                         (5103.f / 18656.f) * k5),
           yp1)  // k6 history is exactly yp1
    bar_lds();

    // ---- stage 6: k6 + y update + dense write + rotate history ----
    MLP3(Hb, Xb, tb + dt)
    k6 = KS;
    {
      float yn = y + dt * ((35.f / 384.f) * k1 + (500.f / 1113.f) * k3 +
                           (125.f / 192.f) * k4 - (2187.f / 6784.f) * k5 +
                           (11.f / 84.f) * k6);
      y = yn;
      if (wr16) gout[obt + (size_t)(n + 1) * D + d] = yn;
      yp0 = np0;
      yp1 = np1;
      XWRITE(Xb, yn, yp0)  // next step's k1 input
    }
    bar_lds();
  }
#undef MLP3
#undef L128
#undef XWRITE
}

extern "C" void kernel_launch(void* const* d_in, const int* in_sizes, int n_in,
                              void* d_out, int out_size, void* d_ws, size_t ws_size,
                              hipStream_t stream) {
  const float* ts = (const float*)d_in[0];
  const float* y0 = (const float*)d_in[1];
  const float* W1 = (const float*)d_in[2];
  const float* b1 = (const float*)d_in[3];
  const float* W2 = (const float*)d_in[4];
  const float* b2 = (const float*)d_in[5];
  const float* W3 = (const float*)d_in[6];
  const float* b3 = (const float*)d_in[7];
  float* out = (float*)d_out;

  hipLaunchKernelGGL(NeuralDDEWithTime_46823733461186_kernel,
                     dim3(BATCH), dim3(TPB), 0, stream,
                     ts, y0, W1, b1, W2, b2, W3, b3, out);
}